// Round 4
// baseline (479.719 us; speedup 1.0000x reference)
//
#include <hip/hip_runtime.h>

#define NFEAT 256
#define NHID 64
#define NHEAD 8
#define HID1 512   // NHEAD*NHID
#define NOUT 128

typedef unsigned short ushort_t;
typedef unsigned int uint_t;
typedef __attribute__((ext_vector_type(8))) short short8;
typedef __attribute__((ext_vector_type(4))) float floatx4;
typedef __attribute__((ext_vector_type(4))) ushort_t ushort4_t;

static __device__ __forceinline__ float bf2f(uint_t s) {
    return __uint_as_float(s << 16);
}
static __device__ __forceinline__ ushort_t f2bf(float f) {
    uint_t u = __float_as_uint(f);
    u += 0x7FFF + ((u >> 16) & 1);   // RNE; inputs finite
    return (ushort_t)(u >> 16);
}
static __device__ __forceinline__ float readlane_f(float v, int l) {
    return __int_as_float(__builtin_amdgcn_readlane(__float_as_int(v), l));
}

// ---------------- CSR build ----------------
__global__ void k_hist(const int* __restrict__ dstA, int E, int n, int* __restrict__ deg) {
    int i = blockIdx.x * blockDim.x + threadIdx.x;
    if (i >= E + n) return;
    int d = (i < E) ? dstA[i] : (i - E);
    atomicAdd(&deg[d], 1);
}

__global__ __launch_bounds__(1024) void k_scan(const int* __restrict__ deg, int* __restrict__ indptr, int n) {
    __shared__ int part[1024];
    int t = threadIdx.x;
    int chunk = (n + 1023) >> 10;
    int b = t * chunk;
    int e = min(b + chunk, n);
    int s = 0;
    for (int i = b; i < e; ++i) s += deg[i];
    part[t] = s;
    __syncthreads();
    for (int off = 1; off < 1024; off <<= 1) {
        int v = (t >= off) ? part[t - off] : 0;
        __syncthreads();
        part[t] += v;
        __syncthreads();
    }
    int run = (t == 0) ? 0 : part[t - 1];
    for (int i = b; i < e; ++i) { indptr[i] = run; run += deg[i]; }
    if (t == 1023) indptr[n] = part[1023];
}

__global__ void k_fill(const int* __restrict__ srcA, const int* __restrict__ dstA, int E, int n,
                       const int* __restrict__ indptr, int* __restrict__ cnt, int* __restrict__ csr_src) {
    int i = blockIdx.x * blockDim.x + threadIdx.x;
    if (i >= E + n) return;
    int s, d;
    if (i < E) { s = srcA[i]; d = dstA[i]; } else { s = i - E; d = s; }
    int pos = indptr[d] + atomicAdd(&cnt[d], 1);
    csr_src[pos] = s;
}

// ---------------- prep: fp32 -> bf16 cast (4 elems/thread) ----------------
__global__ void k_cast(const float* __restrict__ x, ushort_t* __restrict__ xb, int total4) {
    int i = blockIdx.x * blockDim.x + threadIdx.x;
    if (i >= total4) return;
    floatx4 f = ((const floatx4*)x)[i];
    ushort4_t o;
    #pragma unroll
    for (int j = 0; j < 4; ++j) o[j] = f2bf(f[j]);
    ((ushort4_t*)xb)[i] = o;
}

// ---------------- prep: W[K][N] fp32 -> Wt[N][K] bf16 ----------------
__global__ void k_prepw(const float* __restrict__ W, ushort_t* __restrict__ Wt, int K, int N) {
    int i = blockIdx.x * blockDim.x + threadIdx.x;   // i = n*K + k
    if (i >= K * N) return;
    int nn = i / K, kk = i % K;
    Wt[i] = f2bf(W[(size_t)kk * N + nn]);
}

// ---------------- bf16 MFMA GEMM, m97 structure ----------------
__global__ __launch_bounds__(256) void k_gemm128(const ushort_t* __restrict__ A,
                                                 const ushort_t* __restrict__ Bt,
                                                 ushort_t* __restrict__ C,
                                                 int M, int N, int K) {
    __shared__ __align__(16) ushort_t As[128 * 32];
    __shared__ __align__(16) ushort_t Bs[128 * 32];
    const int t = threadIdx.x;
    const int w = t >> 6, lane = t & 63;
    const int l16 = lane & 15, quad = lane >> 4;
    const int m0 = blockIdx.y * 128, n0 = blockIdx.x * 128;
    const int r0 = (w >> 1) * 64;
    const int c0 = (w & 1) * 64;

    floatx4 acc[4][4] = {};

    const int srow[2] = { (0 * 256 + t) >> 2, (1 * 256 + t) >> 2 };
    const int skp = (t & 3) * 8;
    const int wbase0 = (0 * 256 + (t & ~63)) * 8;
    const int wbase1 = (1 * 256 + (t & ~63)) * 8;

    for (int k0 = 0; k0 < K; k0 += 32) {
        {
            int gr0 = m0 + srow[0]; if (gr0 >= M) gr0 = M - 1;
            int gr1 = m0 + srow[1]; if (gr1 >= M) gr1 = M - 1;
            const ushort_t* gpa0 = A + (size_t)gr0 * K + k0 + skp;
            const ushort_t* gpa1 = A + (size_t)gr1 * K + k0 + skp;
            const ushort_t* gpb0 = Bt + (size_t)(n0 + srow[0]) * K + k0 + skp;
            const ushort_t* gpb1 = Bt + (size_t)(n0 + srow[1]) * K + k0 + skp;
            __builtin_amdgcn_global_load_lds((const __attribute__((address_space(1))) void*)gpa0,
                (__attribute__((address_space(3))) void*)(As + wbase0), 16, 0, 0);
            __builtin_amdgcn_global_load_lds((const __attribute__((address_space(1))) void*)gpa1,
                (__attribute__((address_space(3))) void*)(As + wbase1), 16, 0, 0);
            __builtin_amdgcn_global_load_lds((const __attribute__((address_space(1))) void*)gpb0,
                (__attribute__((address_space(3))) void*)(Bs + wbase0), 16, 0, 0);
            __builtin_amdgcn_global_load_lds((const __attribute__((address_space(1))) void*)gpb1,
                (__attribute__((address_space(3))) void*)(Bs + wbase1), 16, 0, 0);
        }
        __syncthreads();

        short8 af[4], bf[4];
        #pragma unroll
        for (int i = 0; i < 4; ++i)
            af[i] = *(const short8*)(As + (r0 + i * 16 + l16) * 32 + quad * 8);
        #pragma unroll
        for (int j = 0; j < 4; ++j)
            bf[j] = *(const short8*)(Bs + (c0 + j * 16 + l16) * 32 + quad * 8);
        #pragma unroll
        for (int i = 0; i < 4; ++i)
            #pragma unroll
            for (int j = 0; j < 4; ++j)
                acc[i][j] = __builtin_amdgcn_mfma_f32_16x16x32_bf16(af[i], bf[j], acc[i][j], 0, 0, 0);
        __syncthreads();
    }

    #pragma unroll
    for (int i = 0; i < 4; ++i) {
        #pragma unroll
        for (int r = 0; r < 4; ++r) {
            int row = m0 + r0 + i * 16 + quad * 4 + r;
            if (row < M) {
                #pragma unroll
                for (int j = 0; j < 4; ++j)
                    C[(size_t)row * N + n0 + c0 + j * 16 + l16] = f2bf(acc[i][j][r]);
            }
        }
    }
}

// ---------------- layer 1 logits from bf16 feat ----------------
__global__ __launch_bounds__(256) void k_elr1(const uint_t* __restrict__ fb, const float* __restrict__ al,
                                              const float* __restrict__ ar, float* __restrict__ el,
                                              float* __restrict__ er, int n) {
    int node = blockIdx.x;
    int t = threadIdx.x;
    uint_t u = fb[(size_t)node * 256 + t];       // elems 2t, 2t+1 (head h = t>>5)
    float lo = bf2f(u & 0xFFFF), hi = bf2f(u >> 16);
    float p = lo * al[2 * t] + hi * al[2 * t + 1];
    float q = lo * ar[2 * t] + hi * ar[2 * t + 1];
    for (int o = 16; o > 0; o >>= 1) {
        p += __shfl_down(p, o, 32);
        q += __shfl_down(q, o, 32);
    }
    if ((t & 31) == 0) {
        int h = t >> 5;
        el[node * NHEAD + h] = p;
        er[node * NHEAD + h] = q;
    }
}

// ---------------- layer 1 aggregate: batch weights one-edge-per-lane, readlane broadcast ----------------
// block = 256 threads = 1 node; thread t covers elems 2t,2t+1 (head h = t>>5).
// Per wave: lanes 0-31 belong to head 2w, lanes 32-63 to head 2w+1.
__global__ __launch_bounds__(256) void k_agg1(const uint_t* __restrict__ fb, const float* __restrict__ el,
                                              const float* __restrict__ er, const float* __restrict__ b1,
                                              const int* __restrict__ indptr, const int* __restrict__ csr_src,
                                              uint_t* __restrict__ h1b, int n) {
    int node = blockIdx.x;
    int t = threadIdx.x;
    int lane = t & 63;
    int h = t >> 5;
    bool hiHalf = (lane & 32) != 0;
    int e0 = indptr[node], e1 = indptr[node + 1];
    int deg = e1 - e0;
    float erv = er[node * NHEAD + h];
    float a0 = 0.f, a1 = 0.f, den = 0.f;

    for (int base = 0; base < deg; base += 32) {
        int cnt = min(32, deg - base);
        int li = lane & 31;
        int sv = 0;
        float wv = 0.f;
        if (li < cnt) {
            sv = csr_src[e0 + base + li];           // edge base+li
            float x = el[sv * NHEAD + h] + erv;     // this lane's own head
            x = (x > 0.f) ? x : 0.2f * x;
            wv = __expf(x);
        }
        for (int j = 0; j < cnt; ++j) {
            int s = __builtin_amdgcn_readlane(sv, j);        // scalar src id
            float wlo = readlane_f(wv, j);
            float whi = readlane_f(wv, j + 32);
            float w = hiHalf ? whi : wlo;
            uint_t u = fb[(size_t)s * 256 + t];
            den += w;
            a0 += w * bf2f(u & 0xFFFF);
            a1 += w * bf2f(u >> 16);
        }
    }

    float inv = 1.f / den;
    float v0 = a0 * inv + b1[2 * t];
    float v1 = a1 * inv + b1[2 * t + 1];
    v0 = (v0 > 0.f) ? v0 : (__expf(v0) - 1.f);
    v1 = (v1 > 0.f) ? v1 : (__expf(v1) - 1.f);
    h1b[(size_t)node * 256 + t] = (uint_t)f2bf(v0) | ((uint_t)f2bf(v1) << 16);
}

// ---------------- layer 2 logits ----------------
__global__ __launch_bounds__(256) void k_elr2(const uint_t* __restrict__ fb2, const float* __restrict__ al2,
                                              const float* __restrict__ ar2, float* __restrict__ el2,
                                              float* __restrict__ er2, int n) {
    int wid = blockIdx.x * 4 + (threadIdx.x >> 6);
    int lane = threadIdx.x & 63;
    if (wid >= n) return;
    uint_t u = fb2[(size_t)wid * 64 + lane];
    float lo = bf2f(u & 0xFFFF), hi = bf2f(u >> 16);
    float p = lo * al2[2 * lane] + hi * al2[2 * lane + 1];
    float q = lo * ar2[2 * lane] + hi * ar2[2 * lane + 1];
    for (int o = 32; o > 0; o >>= 1) { p += __shfl_down(p, o); q += __shfl_down(q, o); }
    if (lane == 0) { el2[wid] = p; er2[wid] = q; }
}

// ---------------- layer 2 aggregate: one wave per node, batched weights ----------------
__global__ __launch_bounds__(256) void k_agg2(const uint_t* __restrict__ fb2, const float* __restrict__ el2,
                                              const float* __restrict__ er2, const float* __restrict__ b2,
                                              const int* __restrict__ indptr, const int* __restrict__ csr_src,
                                              float* __restrict__ out, int n) {
    int wid = blockIdx.x * 4 + (threadIdx.x >> 6);
    int lane = threadIdx.x & 63;
    if (wid >= n) return;
    float erv = er2[wid];
    int e0 = indptr[wid], e1 = indptr[wid + 1];
    int deg = e1 - e0;
    float a0 = 0.f, a1 = 0.f, den = 0.f;

    for (int base = 0; base < deg; base += 64) {
        int cnt = min(64, deg - base);
        int sv = 0;
        float wv = 0.f;
        if (lane < cnt) {
            sv = csr_src[e0 + base + lane];
            float x = el2[sv] + erv;
            x = (x > 0.f) ? x : 0.2f * x;
            wv = __expf(x);
        }
        for (int j = 0; j < cnt; ++j) {
            int s = __builtin_amdgcn_readlane(sv, j);
            float w = readlane_f(wv, j);
            uint_t u = fb2[(size_t)s * 64 + lane];
            den += w;
            a0 += w * bf2f(u & 0xFFFF);
            a1 += w * bf2f(u >> 16);
        }
    }

    float inv = 1.f / den;
    float2 o;
    o.x = a0 * inv + b2[2 * lane];
    o.y = a1 * inv + b2[2 * lane + 1];
    ((float2*)out)[(size_t)wid * 64 + lane] = o;
}

extern "C" void kernel_launch(void* const* d_in, const int* in_sizes, int n_in,
                              void* d_out, int out_size, void* d_ws, size_t ws_size,
                              hipStream_t stream) {
    const float* x   = (const float*)d_in[0];
    const int*   ei  = (const int*)d_in[1];
    const float* W1  = (const float*)d_in[2];
    const float* al1 = (const float*)d_in[3];
    const float* ar1 = (const float*)d_in[4];
    const float* b1  = (const float*)d_in[5];
    const float* W2  = (const float*)d_in[6];
    const float* al2 = (const float*)d_in[7];
    const float* ar2 = (const float*)d_in[8];
    const float* b2  = (const float*)d_in[9];

    const int n  = in_sizes[0] / NFEAT;   // 50000
    const int E  = in_sizes[1] / 2;       // 400000
    const int ET = E + n;
    const int* srcA = ei;
    const int* dstA = ei + E;

    char* ws = (char*)d_ws;
    size_t off = 0;
    auto alloc = [&](size_t bytes) -> void* {
        void* p = ws + off;
        off += (bytes + 255) & ~(size_t)255;
        return p;
    };
    ushort_t* xb     = (ushort_t*)alloc((size_t)n * NFEAT * 2);
    ushort_t* feat1b = (ushort_t*)alloc((size_t)n * HID1 * 2);
    ushort_t* h1b    = (ushort_t*)alloc((size_t)n * HID1 * 2);
    ushort_t* feat2b = (ushort_t*)alloc((size_t)n * NOUT * 2);
    ushort_t* W1t    = (ushort_t*)alloc((size_t)NFEAT * HID1 * 2);
    ushort_t* W2t    = (ushort_t*)alloc((size_t)HID1 * NOUT * 2);
    float* el1 = (float*)alloc((size_t)n * NHEAD * 4);
    float* er1 = (float*)alloc((size_t)n * NHEAD * 4);
    float* el2 = (float*)alloc((size_t)n * 4);
    float* er2 = (float*)alloc((size_t)n * 4);
    int* indptr = (int*)alloc((size_t)(n + 1) * 4);
    int* deg    = (int*)alloc((size_t)n * 4);
    int* cnt    = (int*)alloc((size_t)n * 4);
    int* csr    = (int*)alloc((size_t)ET * 4);

    hipMemsetAsync(deg, 0, (size_t)n * 4, stream);
    hipMemsetAsync(cnt, 0, (size_t)n * 4, stream);

    // CSR build
    k_hist<<<(ET + 255) / 256, 256, 0, stream>>>(dstA, E, n, deg);
    k_scan<<<1, 1024, 0, stream>>>(deg, indptr, n);
    k_fill<<<(ET + 255) / 256, 256, 0, stream>>>(srcA, dstA, E, n, indptr, cnt, csr);

    // prep: cast x, transpose+cast weights
    k_cast<<<((n * NFEAT / 4) + 255) / 256, 256, 0, stream>>>(x, xb, n * NFEAT / 4);
    k_prepw<<<(NFEAT * HID1 + 255) / 256, 256, 0, stream>>>(W1, W1t, NFEAT, HID1);
    k_prepw<<<(HID1 * NOUT + 255) / 256, 256, 0, stream>>>(W2, W2t, HID1, NOUT);

    // layer 1
    k_gemm128<<<dim3(HID1 / 128, (n + 127) / 128), 256, 0, stream>>>(xb, W1t, feat1b, n, HID1, NFEAT);
    k_elr1<<<n, 256, 0, stream>>>((const uint_t*)feat1b, al1, ar1, el1, er1, n);
    k_agg1<<<n, 256, 0, stream>>>((const uint_t*)feat1b, el1, er1, b1, indptr, csr, (uint_t*)h1b, n);

    // layer 2
    k_gemm128<<<dim3(NOUT / 128, (n + 127) / 128), 256, 0, stream>>>(h1b, W2t, feat2b, n, NOUT, HID1);
    k_elr2<<<(n + 3) / 4, 256, 0, stream>>>((const uint_t*)feat2b, al2, ar2, el2, er2, n);
    k_agg2<<<(n + 3) / 4, 256, 0, stream>>>((const uint_t*)feat2b, el2, er2, b2, indptr, csr, (float*)d_out, n);
}

// Round 5
// 442.643 us; speedup vs baseline: 1.0838x; 1.0838x over previous
//
#include <hip/hip_runtime.h>

#define NFEAT 256
#define NHID 64
#define NHEAD 8
#define HID1 512   // NHEAD*NHID
#define NOUT 128

typedef unsigned short ushort_t;
typedef unsigned int uint_t;
typedef __attribute__((ext_vector_type(8))) short short8;
typedef __attribute__((ext_vector_type(4))) float floatx4;
typedef __attribute__((ext_vector_type(4))) ushort_t ushort4_t;

static __device__ __forceinline__ float bf2f(uint_t s) {
    return __uint_as_float(s << 16);
}
static __device__ __forceinline__ ushort_t f2bf(float f) {
    uint_t u = __float_as_uint(f);
    u += 0x7FFF + ((u >> 16) & 1);   // RNE; inputs finite
    return (ushort_t)(u >> 16);
}

// ---------------- CSR build ----------------
__global__ void k_hist(const int* __restrict__ dstA, int E, int n, int* __restrict__ deg) {
    int i = blockIdx.x * blockDim.x + threadIdx.x;
    if (i >= E + n) return;
    int d = (i < E) ? dstA[i] : (i - E);
    atomicAdd(&deg[d], 1);
}

__global__ __launch_bounds__(1024) void k_scan(const int* __restrict__ deg, int* __restrict__ indptr, int n) {
    __shared__ int part[1024];
    int t = threadIdx.x;
    int chunk = (n + 1023) >> 10;
    int b = t * chunk;
    int e = min(b + chunk, n);
    int s = 0;
    for (int i = b; i < e; ++i) s += deg[i];
    part[t] = s;
    __syncthreads();
    for (int off = 1; off < 1024; off <<= 1) {
        int v = (t >= off) ? part[t - off] : 0;
        __syncthreads();
        part[t] += v;
        __syncthreads();
    }
    int run = (t == 0) ? 0 : part[t - 1];
    for (int i = b; i < e; ++i) { indptr[i] = run; run += deg[i]; }
    if (t == 1023) indptr[n] = part[1023];
}

__global__ void k_fill(const int* __restrict__ srcA, const int* __restrict__ dstA, int E, int n,
                       const int* __restrict__ indptr, int* __restrict__ cnt,
                       int* __restrict__ csr_src, int* __restrict__ csr_dst) {
    int i = blockIdx.x * blockDim.x + threadIdx.x;
    if (i >= E + n) return;
    int s, d;
    if (i < E) { s = srcA[i]; d = dstA[i]; } else { s = i - E; d = s; }
    int pos = indptr[d] + atomicAdd(&cnt[d], 1);
    csr_src[pos] = s;
    csr_dst[pos] = d;
}

// ---------------- prep: fp32 -> bf16 cast ----------------
__global__ void k_cast(const float* __restrict__ x, ushort_t* __restrict__ xb, int total4) {
    int i = blockIdx.x * blockDim.x + threadIdx.x;
    if (i >= total4) return;
    floatx4 f = ((const floatx4*)x)[i];
    ushort4_t o;
    #pragma unroll
    for (int j = 0; j < 4; ++j) o[j] = f2bf(f[j]);
    ((ushort4_t*)xb)[i] = o;
}

// ---------------- prep: W[K][N] fp32 -> Wt[N][K] bf16 ----------------
__global__ void k_prepw(const float* __restrict__ W, ushort_t* __restrict__ Wt, int K, int N) {
    int i = blockIdx.x * blockDim.x + threadIdx.x;
    if (i >= K * N) return;
    int nn = i / K, kk = i % K;
    Wt[i] = f2bf(W[(size_t)kk * N + nn]);
}

// ---------------- bf16 MFMA GEMM, m97 structure ----------------
__global__ __launch_bounds__(256) void k_gemm128(const ushort_t* __restrict__ A,
                                                 const ushort_t* __restrict__ Bt,
                                                 ushort_t* __restrict__ C,
                                                 int M, int N, int K) {
    __shared__ __align__(16) ushort_t As[128 * 32];
    __shared__ __align__(16) ushort_t Bs[128 * 32];
    const int t = threadIdx.x;
    const int w = t >> 6, lane = t & 63;
    const int l16 = lane & 15, quad = lane >> 4;
    const int m0 = blockIdx.y * 128, n0 = blockIdx.x * 128;
    const int r0 = (w >> 1) * 64;
    const int c0 = (w & 1) * 64;

    floatx4 acc[4][4] = {};

    const int srow[2] = { (0 * 256 + t) >> 2, (1 * 256 + t) >> 2 };
    const int skp = (t & 3) * 8;
    const int wbase0 = (0 * 256 + (t & ~63)) * 8;
    const int wbase1 = (1 * 256 + (t & ~63)) * 8;

    for (int k0 = 0; k0 < K; k0 += 32) {
        {
            int gr0 = m0 + srow[0]; if (gr0 >= M) gr0 = M - 1;
            int gr1 = m0 + srow[1]; if (gr1 >= M) gr1 = M - 1;
            const ushort_t* gpa0 = A + (size_t)gr0 * K + k0 + skp;
            const ushort_t* gpa1 = A + (size_t)gr1 * K + k0 + skp;
            const ushort_t* gpb0 = Bt + (size_t)(n0 + srow[0]) * K + k0 + skp;
            const ushort_t* gpb1 = Bt + (size_t)(n0 + srow[1]) * K + k0 + skp;
            __builtin_amdgcn_global_load_lds((const __attribute__((address_space(1))) void*)gpa0,
                (__attribute__((address_space(3))) void*)(As + wbase0), 16, 0, 0);
            __builtin_amdgcn_global_load_lds((const __attribute__((address_space(1))) void*)gpa1,
                (__attribute__((address_space(3))) void*)(As + wbase1), 16, 0, 0);
            __builtin_amdgcn_global_load_lds((const __attribute__((address_space(1))) void*)gpb0,
                (__attribute__((address_space(3))) void*)(Bs + wbase0), 16, 0, 0);
            __builtin_amdgcn_global_load_lds((const __attribute__((address_space(1))) void*)gpb1,
                (__attribute__((address_space(3))) void*)(Bs + wbase1), 16, 0, 0);
        }
        __syncthreads();

        short8 af[4], bf[4];
        #pragma unroll
        for (int i = 0; i < 4; ++i)
            af[i] = *(const short8*)(As + (r0 + i * 16 + l16) * 32 + quad * 8);
        #pragma unroll
        for (int j = 0; j < 4; ++j)
            bf[j] = *(const short8*)(Bs + (c0 + j * 16 + l16) * 32 + quad * 8);
        #pragma unroll
        for (int i = 0; i < 4; ++i)
            #pragma unroll
            for (int j = 0; j < 4; ++j)
                acc[i][j] = __builtin_amdgcn_mfma_f32_16x16x32_bf16(af[i], bf[j], acc[i][j], 0, 0, 0);
        __syncthreads();
    }

    #pragma unroll
    for (int i = 0; i < 4; ++i) {
        #pragma unroll
        for (int r = 0; r < 4; ++r) {
            int row = m0 + r0 + i * 16 + quad * 4 + r;
            if (row < M) {
                #pragma unroll
                for (int j = 0; j < 4; ++j)
                    C[(size_t)row * N + n0 + c0 + j * 16 + l16] = f2bf(acc[i][j][r]);
            }
        }
    }
}

// ---------------- layer 1 logits ----------------
__global__ __launch_bounds__(256) void k_elr1(const uint_t* __restrict__ fb, const float* __restrict__ al,
                                              const float* __restrict__ ar, float* __restrict__ el,
                                              float* __restrict__ er, int n) {
    int node = blockIdx.x;
    int t = threadIdx.x;
    uint_t u = fb[(size_t)node * 256 + t];
    float lo = bf2f(u & 0xFFFF), hi = bf2f(u >> 16);
    float p = lo * al[2 * t] + hi * al[2 * t + 1];
    float q = lo * ar[2 * t] + hi * ar[2 * t + 1];
    for (int o = 16; o > 0; o >>= 1) {
        p += __shfl_down(p, o, 32);
        q += __shfl_down(q, o, 32);
    }
    if ((t & 31) == 0) {
        int h = t >> 5;
        el[node * NHEAD + h] = p;
        er[node * NHEAD + h] = q;
    }
}

// ---------------- edge weights layer 1: one thread per (csr pos, head) ----------------
__global__ void k_wgt1(const int* __restrict__ csr_src, const int* __restrict__ csr_dst,
                       const float* __restrict__ el, const float* __restrict__ er,
                       float* __restrict__ wcsr, int ET) {
    int idx = blockIdx.x * blockDim.x + threadIdx.x;
    if (idx >= ET * NHEAD) return;
    int e = idx >> 3, h = idx & 7;
    int s = csr_src[e], d = csr_dst[e];
    float x = el[s * NHEAD + h] + er[d * NHEAD + h];
    x = (x > 0.f) ? x : 0.2f * x;
    wcsr[idx] = __expf(x);
}

// ---------------- edge weights layer 2: one thread per csr pos ----------------
__global__ void k_wgt2(const int* __restrict__ csr_src, const int* __restrict__ csr_dst,
                       const float* __restrict__ el2, const float* __restrict__ er2,
                       float* __restrict__ wcsr, int ET) {
    int e = blockIdx.x * blockDim.x + threadIdx.x;
    if (e >= ET) return;
    int s = csr_src[e], d = csr_dst[e];
    float x = el2[s] + er2[d];
    x = (x > 0.f) ? x : 0.2f * x;
    wcsr[e] = __expf(x);
}

// ---------------- layer 1 aggregate: precomputed weights, 4-way unroll ----------------
// block = 256 threads = 1 node; thread t covers elems 2t,2t+1 (head h = t>>5).
__global__ __launch_bounds__(256) void k_agg1(const uint_t* __restrict__ fb, const float* __restrict__ wcsr,
                                              const float* __restrict__ b1,
                                              const int* __restrict__ indptr, const int* __restrict__ csr_src,
                                              uint_t* __restrict__ h1b, int n) {
    int node = blockIdx.x;
    int t = threadIdx.x;
    int h = t >> 5;
    int e0 = indptr[node], e1 = indptr[node + 1];
    float a0 = 0.f, a1 = 0.f, den = 0.f;
    int e = e0;
    for (; e + 3 < e1; e += 4) {
        int s0 = csr_src[e], s1 = csr_src[e + 1], s2 = csr_src[e + 2], s3 = csr_src[e + 3];
        float w0 = wcsr[(size_t)e * NHEAD + h];
        float w1 = wcsr[(size_t)(e + 1) * NHEAD + h];
        float w2 = wcsr[(size_t)(e + 2) * NHEAD + h];
        float w3 = wcsr[(size_t)(e + 3) * NHEAD + h];
        uint_t u0 = fb[(size_t)s0 * 256 + t];
        uint_t u1 = fb[(size_t)s1 * 256 + t];
        uint_t u2 = fb[(size_t)s2 * 256 + t];
        uint_t u3 = fb[(size_t)s3 * 256 + t];
        den += (w0 + w1) + (w2 + w3);
        a0 += w0 * bf2f(u0 & 0xFFFF) + w1 * bf2f(u1 & 0xFFFF)
            + w2 * bf2f(u2 & 0xFFFF) + w3 * bf2f(u3 & 0xFFFF);
        a1 += w0 * bf2f(u0 >> 16) + w1 * bf2f(u1 >> 16)
            + w2 * bf2f(u2 >> 16) + w3 * bf2f(u3 >> 16);
    }
    for (; e < e1; ++e) {
        int s = csr_src[e];
        float w = wcsr[(size_t)e * NHEAD + h];
        uint_t u = fb[(size_t)s * 256 + t];
        den += w;
        a0 += w * bf2f(u & 0xFFFF);
        a1 += w * bf2f(u >> 16);
    }
    float inv = 1.f / den;
    float v0 = a0 * inv + b1[2 * t];
    float v1 = a1 * inv + b1[2 * t + 1];
    v0 = (v0 > 0.f) ? v0 : (__expf(v0) - 1.f);
    v1 = (v1 > 0.f) ? v1 : (__expf(v1) - 1.f);
    h1b[(size_t)node * 256 + t] = (uint_t)f2bf(v0) | ((uint_t)f2bf(v1) << 16);
}

// ---------------- layer 2 logits ----------------
__global__ __launch_bounds__(256) void k_elr2(const uint_t* __restrict__ fb2, const float* __restrict__ al2,
                                              const float* __restrict__ ar2, float* __restrict__ el2,
                                              float* __restrict__ er2, int n) {
    int wid = blockIdx.x * 4 + (threadIdx.x >> 6);
    int lane = threadIdx.x & 63;
    if (wid >= n) return;
    uint_t u = fb2[(size_t)wid * 64 + lane];
    float lo = bf2f(u & 0xFFFF), hi = bf2f(u >> 16);
    float p = lo * al2[2 * lane] + hi * al2[2 * lane + 1];
    float q = lo * ar2[2 * lane] + hi * ar2[2 * lane + 1];
    for (int o = 32; o > 0; o >>= 1) { p += __shfl_down(p, o); q += __shfl_down(q, o); }
    if (lane == 0) { el2[wid] = p; er2[wid] = q; }
}

// ---------------- layer 2 aggregate: precomputed weights, 4-way unroll ----------------
__global__ __launch_bounds__(256) void k_agg2(const uint_t* __restrict__ fb2, const float* __restrict__ wcsr,
                                              const float* __restrict__ b2,
                                              const int* __restrict__ indptr, const int* __restrict__ csr_src,
                                              float* __restrict__ out, int n) {
    int wid = blockIdx.x * 4 + (threadIdx.x >> 6);
    int lane = threadIdx.x & 63;
    if (wid >= n) return;
    int e0 = indptr[wid], e1 = indptr[wid + 1];
    float a0 = 0.f, a1 = 0.f, den = 0.f;
    int e = e0;
    for (; e + 3 < e1; e += 4) {
        int s0 = csr_src[e], s1 = csr_src[e + 1], s2 = csr_src[e + 2], s3 = csr_src[e + 3];
        float w0 = wcsr[e], w1 = wcsr[e + 1], w2 = wcsr[e + 2], w3 = wcsr[e + 3];
        uint_t u0 = fb2[(size_t)s0 * 64 + lane];
        uint_t u1 = fb2[(size_t)s1 * 64 + lane];
        uint_t u2 = fb2[(size_t)s2 * 64 + lane];
        uint_t u3 = fb2[(size_t)s3 * 64 + lane];
        den += (w0 + w1) + (w2 + w3);
        a0 += w0 * bf2f(u0 & 0xFFFF) + w1 * bf2f(u1 & 0xFFFF)
            + w2 * bf2f(u2 & 0xFFFF) + w3 * bf2f(u3 & 0xFFFF);
        a1 += w0 * bf2f(u0 >> 16) + w1 * bf2f(u1 >> 16)
            + w2 * bf2f(u2 >> 16) + w3 * bf2f(u3 >> 16);
    }
    for (; e < e1; ++e) {
        int s = csr_src[e];
        float w = wcsr[e];
        uint_t u = fb2[(size_t)s * 64 + lane];
        den += w;
        a0 += w * bf2f(u & 0xFFFF);
        a1 += w * bf2f(u >> 16);
    }
    float inv = 1.f / den;
    float2 o;
    o.x = a0 * inv + b2[2 * lane];
    o.y = a1 * inv + b2[2 * lane + 1];
    ((float2*)out)[(size_t)wid * 64 + lane] = o;
}

extern "C" void kernel_launch(void* const* d_in, const int* in_sizes, int n_in,
                              void* d_out, int out_size, void* d_ws, size_t ws_size,
                              hipStream_t stream) {
    const float* x   = (const float*)d_in[0];
    const int*   ei  = (const int*)d_in[1];
    const float* W1  = (const float*)d_in[2];
    const float* al1 = (const float*)d_in[3];
    const float* ar1 = (const float*)d_in[4];
    const float* b1  = (const float*)d_in[5];
    const float* W2  = (const float*)d_in[6];
    const float* al2 = (const float*)d_in[7];
    const float* ar2 = (const float*)d_in[8];
    const float* b2  = (const float*)d_in[9];

    const int n  = in_sizes[0] / NFEAT;   // 50000
    const int E  = in_sizes[1] / 2;       // 400000
    const int ET = E + n;
    const int* srcA = ei;
    const int* dstA = ei + E;

    char* ws = (char*)d_ws;
    size_t off = 0;
    auto alloc = [&](size_t bytes) -> void* {
        void* p = ws + off;
        off += (bytes + 255) & ~(size_t)255;
        return p;
    };
    ushort_t* xb     = (ushort_t*)alloc((size_t)n * NFEAT * 2);
    ushort_t* feat1b = (ushort_t*)alloc((size_t)n * HID1 * 2);
    ushort_t* h1b    = (ushort_t*)alloc((size_t)n * HID1 * 2);
    ushort_t* feat2b = (ushort_t*)alloc((size_t)n * NOUT * 2);
    ushort_t* W1t    = (ushort_t*)alloc((size_t)NFEAT * HID1 * 2);
    ushort_t* W2t    = (ushort_t*)alloc((size_t)HID1 * NOUT * 2);
    float* el1 = (float*)alloc((size_t)n * NHEAD * 4);
    float* er1 = (float*)alloc((size_t)n * NHEAD * 4);
    float* el2 = (float*)alloc((size_t)n * 4);
    float* er2 = (float*)alloc((size_t)n * 4);
    float* wcsr1 = (float*)alloc((size_t)ET * NHEAD * 4);   // 14.4 MB
    float* wcsr2 = (float*)alloc((size_t)ET * 4);           // 1.8 MB
    int* indptr  = (int*)alloc((size_t)(n + 1) * 4);
    int* deg     = (int*)alloc((size_t)n * 4);
    int* cnt     = (int*)alloc((size_t)n * 4);
    int* csr     = (int*)alloc((size_t)ET * 4);
    int* csrd    = (int*)alloc((size_t)ET * 4);

    hipMemsetAsync(deg, 0, (size_t)n * 4, stream);
    hipMemsetAsync(cnt, 0, (size_t)n * 4, stream);

    // CSR build
    k_hist<<<(ET + 255) / 256, 256, 0, stream>>>(dstA, E, n, deg);
    k_scan<<<1, 1024, 0, stream>>>(deg, indptr, n);
    k_fill<<<(ET + 255) / 256, 256, 0, stream>>>(srcA, dstA, E, n, indptr, cnt, csr, csrd);

    // prep: cast x, transpose+cast weights
    k_cast<<<((n * NFEAT / 4) + 255) / 256, 256, 0, stream>>>(x, xb, n * NFEAT / 4);
    k_prepw<<<(NFEAT * HID1 + 255) / 256, 256, 0, stream>>>(W1, W1t, NFEAT, HID1);
    k_prepw<<<(HID1 * NOUT + 255) / 256, 256, 0, stream>>>(W2, W2t, HID1, NOUT);

    // layer 1
    k_gemm128<<<dim3(HID1 / 128, (n + 127) / 128), 256, 0, stream>>>(xb, W1t, feat1b, n, HID1, NFEAT);
    k_elr1<<<n, 256, 0, stream>>>((const uint_t*)feat1b, al1, ar1, el1, er1, n);
    k_wgt1<<<(ET * NHEAD + 255) / 256, 256, 0, stream>>>(csr, csrd, el1, er1, wcsr1, ET);
    k_agg1<<<n, 256, 0, stream>>>((const uint_t*)feat1b, wcsr1, b1, indptr, csr, (uint_t*)h1b, n);

    // layer 2
    k_gemm128<<<dim3(NOUT / 128, (n + 127) / 128), 256, 0, stream>>>(h1b, W2t, feat2b, n, NOUT, HID1);
    k_elr2<<<(n + 3) / 4, 256, 0, stream>>>((const uint_t*)feat2b, al2, ar2, el2, er2, n);
    k_wgt2<<<(ET + 255) / 256, 256, 0, stream>>>(csr, csrd, el2, er2, wcsr2, ET);
    k_agg2<<<(n + 3) / 4, 256, 0, stream>>>((const uint_t*)feat2b, wcsr2, b2, indptr, csr, (float*)d_out, n);
}

// Round 6
// 386.734 us; speedup vs baseline: 1.2404x; 1.1446x over previous
//
#include <hip/hip_runtime.h>

#define NFEAT 256
#define NHID 64
#define NHEAD 8
#define HID1 512   // NHEAD*NHID
#define NOUT 128

typedef unsigned short ushort_t;
typedef unsigned int uint_t;
typedef __attribute__((ext_vector_type(8))) short short8;
typedef __attribute__((ext_vector_type(4))) float floatx4;
typedef __attribute__((ext_vector_type(4))) ushort_t ushort4_t;

static __device__ __forceinline__ float bf2f(uint_t s) {
    return __uint_as_float(s << 16);
}
static __device__ __forceinline__ ushort_t f2bf(float f) {
    uint_t u = __float_as_uint(f);
    u += 0x7FFF + ((u >> 16) & 1);   // RNE; inputs finite
    return (ushort_t)(u >> 16);
}

// ---------------- fused prep: cast x, transpose W1/W2, degree histogram ----------------
// block ranges: [0,c0) cast, [c0,c1) W1t, [c1,c2) W2t, [c2,...) hist
__global__ void k_prep(const float* __restrict__ x, ushort_t* __restrict__ xb,
                       const float* __restrict__ W1, ushort_t* __restrict__ W1t,
                       const float* __restrict__ W2, ushort_t* __restrict__ W2t,
                       const int* __restrict__ dstA, int* __restrict__ deg,
                       int n, int E, int c0, int c1, int c2) {
    int blk = blockIdx.x;
    int t = threadIdx.x;
    if (blk < c0) {                       // cast x -> bf16, 4 elems/thread
        int i = blk * 256 + t;
        floatx4 f = ((const floatx4*)x)[i];
        ushort4_t o;
        #pragma unroll
        for (int j = 0; j < 4; ++j) o[j] = f2bf(f[j]);
        ((ushort4_t*)xb)[i] = o;
    } else if (blk < c1) {                // W1[K][N] -> W1t[N][K] bf16
        int i = (blk - c0) * 256 + t;     // i = nn*K + kk, K=NFEAT, N=HID1
        int nn = i / NFEAT, kk = i % NFEAT;
        W1t[i] = f2bf(W1[(size_t)kk * HID1 + nn]);
    } else if (blk < c2) {                // W2[K][N] -> W2t[N][K] bf16
        int i = (blk - c1) * 256 + t;     // K=HID1, N=NOUT
        int nn = i / HID1, kk = i % HID1;
        W2t[i] = f2bf(W2[(size_t)kk * NOUT + nn]);
    } else {                              // degree histogram (self-loops appended)
        int i = (blk - c2) * 256 + t;
        if (i < E + n) {
            int d = (i < E) ? dstA[i] : (i - E);
            atomicAdd(&deg[d], 1);
        }
    }
}

// ---------------- single-block scan (4x unrolled phases) ----------------
__global__ __launch_bounds__(1024) void k_scan(const int* __restrict__ deg, int* __restrict__ indptr, int n) {
    __shared__ int part[1024];
    int t = threadIdx.x;
    int chunk = (n + 1023) >> 10;
    int b = t * chunk;
    int e = min(b + chunk, n);
    int s = 0;
    int i = b;
    for (; i + 3 < e; i += 4)
        s += (deg[i] + deg[i + 1]) + (deg[i + 2] + deg[i + 3]);
    for (; i < e; ++i) s += deg[i];
    part[t] = s;
    __syncthreads();
    for (int off = 1; off < 1024; off <<= 1) {
        int v = (t >= off) ? part[t - off] : 0;
        __syncthreads();
        part[t] += v;
        __syncthreads();
    }
    int run = (t == 0) ? 0 : part[t - 1];
    i = b;
    for (; i + 3 < e; i += 4) {
        int d0 = deg[i], d1 = deg[i + 1], d2 = deg[i + 2], d3 = deg[i + 3];
        indptr[i] = run; run += d0;
        indptr[i + 1] = run; run += d1;
        indptr[i + 2] = run; run += d2;
        indptr[i + 3] = run; run += d3;
    }
    for (; i < e; ++i) { indptr[i] = run; run += deg[i]; }
    if (t == 1023) indptr[n] = part[1023];
}

__global__ void k_fill(const int* __restrict__ srcA, const int* __restrict__ dstA, int E, int n,
                       const int* __restrict__ indptr, int* __restrict__ cnt,
                       int* __restrict__ csr_src, int* __restrict__ csr_dst) {
    int i = blockIdx.x * blockDim.x + threadIdx.x;
    if (i >= E + n) return;
    int s, d;
    if (i < E) { s = srcA[i]; d = dstA[i]; } else { s = i - E; d = s; }
    int pos = indptr[d] + atomicAdd(&cnt[d], 1);
    csr_src[pos] = s;
    csr_dst[pos] = d;
}

// ---------------- GEMM1: 128x128 tile + fused el1/er1 epilogue ----------------
// C[M,512] = A[M,256] @ Bt[512,256]^T (bf16). Each N-block covers exactly 2 heads
// (64 cols each), so el/er reduce within-wave over l16 — no atomics.
__global__ __launch_bounds__(256) void k_gemm1(const ushort_t* __restrict__ A,
                                               const ushort_t* __restrict__ Bt,
                                               ushort_t* __restrict__ C,
                                               const float* __restrict__ al,
                                               const float* __restrict__ ar,
                                               float* __restrict__ el, float* __restrict__ er,
                                               int M) {
    const int N = HID1, K = NFEAT;
    __shared__ __align__(16) ushort_t As[128 * 32];
    __shared__ __align__(16) ushort_t Bs[128 * 32];
    const int t = threadIdx.x;
    const int w = t >> 6, lane = t & 63;
    const int l16 = lane & 15, quad = lane >> 4;
    const int m0 = blockIdx.y * 128, n0 = blockIdx.x * 128;
    const int r0 = (w >> 1) * 64;
    const int c0 = (w & 1) * 64;

    floatx4 acc[4][4] = {};

    const int srow[2] = { (0 * 256 + t) >> 2, (1 * 256 + t) >> 2 };
    const int skp = (t & 3) * 8;
    const int wbase0 = (0 * 256 + (t & ~63)) * 8;
    const int wbase1 = (1 * 256 + (t & ~63)) * 8;

    for (int k0 = 0; k0 < K; k0 += 32) {
        int gr0 = m0 + srow[0]; if (gr0 >= M) gr0 = M - 1;
        int gr1 = m0 + srow[1]; if (gr1 >= M) gr1 = M - 1;
        const ushort_t* gpa0 = A + (size_t)gr0 * K + k0 + skp;
        const ushort_t* gpa1 = A + (size_t)gr1 * K + k0 + skp;
        const ushort_t* gpb0 = Bt + (size_t)(n0 + srow[0]) * K + k0 + skp;
        const ushort_t* gpb1 = Bt + (size_t)(n0 + srow[1]) * K + k0 + skp;
        __builtin_amdgcn_global_load_lds((const __attribute__((address_space(1))) void*)gpa0,
            (__attribute__((address_space(3))) void*)(As + wbase0), 16, 0, 0);
        __builtin_amdgcn_global_load_lds((const __attribute__((address_space(1))) void*)gpa1,
            (__attribute__((address_space(3))) void*)(As + wbase1), 16, 0, 0);
        __builtin_amdgcn_global_load_lds((const __attribute__((address_space(1))) void*)gpb0,
            (__attribute__((address_space(3))) void*)(Bs + wbase0), 16, 0, 0);
        __builtin_amdgcn_global_load_lds((const __attribute__((address_space(1))) void*)gpb1,
            (__attribute__((address_space(3))) void*)(Bs + wbase1), 16, 0, 0);
        __syncthreads();

        short8 af[4], bf[4];
        #pragma unroll
        for (int i = 0; i < 4; ++i)
            af[i] = *(const short8*)(As + (r0 + i * 16 + l16) * 32 + quad * 8);
        #pragma unroll
        for (int j = 0; j < 4; ++j)
            bf[j] = *(const short8*)(Bs + (c0 + j * 16 + l16) * 32 + quad * 8);
        #pragma unroll
        for (int i = 0; i < 4; ++i)
            #pragma unroll
            for (int j = 0; j < 4; ++j)
                acc[i][j] = __builtin_amdgcn_mfma_f32_16x16x32_bf16(af[i], bf[j], acc[i][j], 0, 0, 0);
        __syncthreads();
    }

    // C store
    #pragma unroll
    for (int i = 0; i < 4; ++i) {
        #pragma unroll
        for (int r = 0; r < 4; ++r) {
            int row = m0 + r0 + i * 16 + quad * 4 + r;
            if (row < M) {
                #pragma unroll
                for (int j = 0; j < 4; ++j)
                    C[(size_t)row * N + n0 + c0 + j * 16 + l16] = f2bf(acc[i][j][r]);
            }
        }
    }

    // fused el/er: head = (n0+c0)/64; this thread's cols are n0+c0+j*16+l16
    float alv[4], arv[4];
    #pragma unroll
    for (int j = 0; j < 4; ++j) {
        int col = n0 + c0 + j * 16 + l16;
        alv[j] = al[col];
        arv[j] = ar[col];
    }
    int head = (n0 + c0) >> 6;
    #pragma unroll
    for (int i = 0; i < 4; ++i) {
        #pragma unroll
        for (int r = 0; r < 4; ++r) {
            float p = acc[i][0][r] * alv[0] + acc[i][1][r] * alv[1]
                    + acc[i][2][r] * alv[2] + acc[i][3][r] * alv[3];
            float q = acc[i][0][r] * arv[0] + acc[i][1][r] * arv[1]
                    + acc[i][2][r] * arv[2] + acc[i][3][r] * arv[3];
            #pragma unroll
            for (int o = 8; o > 0; o >>= 1) {
                p += __shfl_down(p, o);
                q += __shfl_down(q, o);
            }
            if (l16 == 0) {
                int row = m0 + r0 + i * 16 + quad * 4 + r;
                if (row < M) {
                    el[row * NHEAD + head] = p;
                    er[row * NHEAD + head] = q;
                }
            }
        }
    }
}

// ---------------- GEMM2: 64x128 tile + fused el2/er2 epilogue ----------------
// C[M,128] = A[M,512] @ Bt[128,512]^T. grid.x==1 (block covers all 128 cols),
// so el2/er2 combine the two column-half waves through LDS.
__global__ __launch_bounds__(256) void k_gemm2(const ushort_t* __restrict__ A,
                                               const ushort_t* __restrict__ Bt,
                                               ushort_t* __restrict__ C,
                                               const float* __restrict__ al,
                                               const float* __restrict__ ar,
                                               float* __restrict__ el, float* __restrict__ er,
                                               int M) {
    const int N = NOUT, K = HID1;
    __shared__ __align__(16) ushort_t As[64 * 32];
    __shared__ __align__(16) ushort_t Bs[128 * 32];
    __shared__ float elp[64][2], erp[64][2];
    const int t = threadIdx.x;
    const int w = t >> 6, lane = t & 63;
    const int l16 = lane & 15, quad = lane >> 4;
    const int m0 = blockIdx.y * 64;
    const int r0 = (w >> 1) * 32;
    const int c0 = (w & 1) * 64;

    floatx4 acc[2][4] = {};

    const int arow = t >> 2;                  // 0..63
    const int brow[2] = { (0 * 256 + t) >> 2, (1 * 256 + t) >> 2 };
    const int skp = (t & 3) * 8;
    const int wbaseA = (t & ~63) * 8;
    const int wbase0 = (0 * 256 + (t & ~63)) * 8;
    const int wbase1 = (1 * 256 + (t & ~63)) * 8;

    for (int k0 = 0; k0 < K; k0 += 32) {
        int gr = m0 + arow; if (gr >= M) gr = M - 1;
        const ushort_t* gpa = A + (size_t)gr * K + k0 + skp;
        const ushort_t* gpb0 = Bt + (size_t)brow[0] * K + k0 + skp;
        const ushort_t* gpb1 = Bt + (size_t)brow[1] * K + k0 + skp;
        __builtin_amdgcn_global_load_lds((const __attribute__((address_space(1))) void*)gpa,
            (__attribute__((address_space(3))) void*)(As + wbaseA), 16, 0, 0);
        __builtin_amdgcn_global_load_lds((const __attribute__((address_space(1))) void*)gpb0,
            (__attribute__((address_space(3))) void*)(Bs + wbase0), 16, 0, 0);
        __builtin_amdgcn_global_load_lds((const __attribute__((address_space(1))) void*)gpb1,
            (__attribute__((address_space(3))) void*)(Bs + wbase1), 16, 0, 0);
        __syncthreads();

        short8 af[2], bf[4];
        #pragma unroll
        for (int i = 0; i < 2; ++i)
            af[i] = *(const short8*)(As + (r0 + i * 16 + l16) * 32 + quad * 8);
        #pragma unroll
        for (int j = 0; j < 4; ++j)
            bf[j] = *(const short8*)(Bs + (c0 + j * 16 + l16) * 32 + quad * 8);
        #pragma unroll
        for (int i = 0; i < 2; ++i)
            #pragma unroll
            for (int j = 0; j < 4; ++j)
                acc[i][j] = __builtin_amdgcn_mfma_f32_16x16x32_bf16(af[i], bf[j], acc[i][j], 0, 0, 0);
        __syncthreads();
    }

    float alv[4], arv[4];
    #pragma unroll
    for (int j = 0; j < 4; ++j) {
        int col = c0 + j * 16 + l16;
        alv[j] = al[col];
        arv[j] = ar[col];
    }
    #pragma unroll
    for (int i = 0; i < 2; ++i) {
        #pragma unroll
        for (int r = 0; r < 4; ++r) {
            int lrow = r0 + i * 16 + quad * 4 + r;
            int row = m0 + lrow;
            if (row < M) {
                #pragma unroll
                for (int j = 0; j < 4; ++j)
                    C[(size_t)row * N + c0 + j * 16 + l16] = f2bf(acc[i][j][r]);
            }
            float p = acc[i][0][r] * alv[0] + acc[i][1][r] * alv[1]
                    + acc[i][2][r] * alv[2] + acc[i][3][r] * alv[3];
            float q = acc[i][0][r] * arv[0] + acc[i][1][r] * arv[1]
                    + acc[i][2][r] * arv[2] + acc[i][3][r] * arv[3];
            #pragma unroll
            for (int o = 8; o > 0; o >>= 1) {
                p += __shfl_down(p, o);
                q += __shfl_down(q, o);
            }
            if (l16 == 0) {
                elp[lrow][w & 1] = p;
                erp[lrow][w & 1] = q;
            }
        }
    }
    __syncthreads();
    if (t < 64) {
        int row = m0 + t;
        if (row < M) {
            el[row] = elp[t][0] + elp[t][1];
            er[row] = erp[t][0] + erp[t][1];
        }
    }
}

// ---------------- edge weights ----------------
__global__ void k_wgt1(const int* __restrict__ csr_src, const int* __restrict__ csr_dst,
                       const float* __restrict__ el, const float* __restrict__ er,
                       float* __restrict__ wcsr, int ET) {
    int idx = blockIdx.x * blockDim.x + threadIdx.x;
    if (idx >= ET * NHEAD) return;
    int e = idx >> 3, h = idx & 7;
    int s = csr_src[e], d = csr_dst[e];
    float x = el[s * NHEAD + h] + er[d * NHEAD + h];
    x = (x > 0.f) ? x : 0.2f * x;
    wcsr[idx] = __expf(x);
}

__global__ void k_wgt2(const int* __restrict__ csr_src, const int* __restrict__ csr_dst,
                       const float* __restrict__ el2, const float* __restrict__ er2,
                       float* __restrict__ wcsr, int ET) {
    int e = blockIdx.x * blockDim.x + threadIdx.x;
    if (e >= ET) return;
    int s = csr_src[e], d = csr_dst[e];
    float x = el2[s] + er2[d];
    x = (x > 0.f) ? x : 0.2f * x;
    wcsr[e] = __expf(x);
}

// ---------------- layer 1 aggregate: precomputed weights, 4-way unroll ----------------
__global__ __launch_bounds__(256) void k_agg1(const uint_t* __restrict__ fb, const float* __restrict__ wcsr,
                                              const float* __restrict__ b1,
                                              const int* __restrict__ indptr, const int* __restrict__ csr_src,
                                              uint_t* __restrict__ h1b, int n) {
    int node = blockIdx.x;
    int t = threadIdx.x;
    int h = t >> 5;
    int e0 = indptr[node], e1 = indptr[node + 1];
    float a0 = 0.f, a1 = 0.f, den = 0.f;
    int e = e0;
    for (; e + 3 < e1; e += 4) {
        int s0 = csr_src[e], s1 = csr_src[e + 1], s2 = csr_src[e + 2], s3 = csr_src[e + 3];
        float w0 = wcsr[(size_t)e * NHEAD + h];
        float w1 = wcsr[(size_t)(e + 1) * NHEAD + h];
        float w2 = wcsr[(size_t)(e + 2) * NHEAD + h];
        float w3 = wcsr[(size_t)(e + 3) * NHEAD + h];
        uint_t u0 = fb[(size_t)s0 * 256 + t];
        uint_t u1 = fb[(size_t)s1 * 256 + t];
        uint_t u2 = fb[(size_t)s2 * 256 + t];
        uint_t u3 = fb[(size_t)s3 * 256 + t];
        den += (w0 + w1) + (w2 + w3);
        a0 += w0 * bf2f(u0 & 0xFFFF) + w1 * bf2f(u1 & 0xFFFF)
            + w2 * bf2f(u2 & 0xFFFF) + w3 * bf2f(u3 & 0xFFFF);
        a1 += w0 * bf2f(u0 >> 16) + w1 * bf2f(u1 >> 16)
            + w2 * bf2f(u2 >> 16) + w3 * bf2f(u3 >> 16);
    }
    for (; e < e1; ++e) {
        int s = csr_src[e];
        float w = wcsr[(size_t)e * NHEAD + h];
        uint_t u = fb[(size_t)s * 256 + t];
        den += w;
        a0 += w * bf2f(u & 0xFFFF);
        a1 += w * bf2f(u >> 16);
    }
    float inv = 1.f / den;
    float v0 = a0 * inv + b1[2 * t];
    float v1 = a1 * inv + b1[2 * t + 1];
    v0 = (v0 > 0.f) ? v0 : (__expf(v0) - 1.f);
    v1 = (v1 > 0.f) ? v1 : (__expf(v1) - 1.f);
    h1b[(size_t)node * 256 + t] = (uint_t)f2bf(v0) | ((uint_t)f2bf(v1) << 16);
}

// ---------------- layer 2 aggregate: precomputed weights, 4-way unroll ----------------
__global__ __launch_bounds__(256) void k_agg2(const uint_t* __restrict__ fb2, const float* __restrict__ wcsr,
                                              const float* __restrict__ b2,
                                              const int* __restrict__ indptr, const int* __restrict__ csr_src,
                                              float* __restrict__ out, int n) {
    int wid = blockIdx.x * 4 + (threadIdx.x >> 6);
    int lane = threadIdx.x & 63;
    if (wid >= n) return;
    int e0 = indptr[wid], e1 = indptr[wid + 1];
    float a0 = 0.f, a1 = 0.f, den = 0.f;
    int e = e0;
    for (; e + 3 < e1; e += 4) {
        int s0 = csr_src[e], s1 = csr_src[e + 1], s2 = csr_src[e + 2], s3 = csr_src[e + 3];
        float w0 = wcsr[e], w1 = wcsr[e + 1], w2 = wcsr[e + 2], w3 = wcsr[e + 3];
        uint_t u0 = fb2[(size_t)s0 * 64 + lane];
        uint_t u1 = fb2[(size_t)s1 * 64 + lane];
        uint_t u2 = fb2[(size_t)s2 * 64 + lane];
        uint_t u3 = fb2[(size_t)s3 * 64 + lane];
        den += (w0 + w1) + (w2 + w3);
        a0 += w0 * bf2f(u0 & 0xFFFF) + w1 * bf2f(u1 & 0xFFFF)
            + w2 * bf2f(u2 & 0xFFFF) + w3 * bf2f(u3 & 0xFFFF);
        a1 += w0 * bf2f(u0 >> 16) + w1 * bf2f(u1 >> 16)
            + w2 * bf2f(u2 >> 16) + w3 * bf2f(u3 >> 16);
    }
    for (; e < e1; ++e) {
        int s = csr_src[e];
        float w = wcsr[e];
        uint_t u = fb2[(size_t)s * 64 + lane];
        den += w;
        a0 += w * bf2f(u & 0xFFFF);
        a1 += w * bf2f(u >> 16);
    }
    float inv = 1.f / den;
    float2 o;
    o.x = a0 * inv + b2[2 * lane];
    o.y = a1 * inv + b2[2 * lane + 1];
    ((float2*)out)[(size_t)wid * 64 + lane] = o;
}

extern "C" void kernel_launch(void* const* d_in, const int* in_sizes, int n_in,
                              void* d_out, int out_size, void* d_ws, size_t ws_size,
                              hipStream_t stream) {
    const float* x   = (const float*)d_in[0];
    const int*   ei  = (const int*)d_in[1];
    const float* W1  = (const float*)d_in[2];
    const float* al1 = (const float*)d_in[3];
    const float* ar1 = (const float*)d_in[4];
    const float* b1  = (const float*)d_in[5];
    const float* W2  = (const float*)d_in[6];
    const float* al2 = (const float*)d_in[7];
    const float* ar2 = (const float*)d_in[8];
    const float* b2  = (const float*)d_in[9];

    const int n  = in_sizes[0] / NFEAT;   // 50000
    const int E  = in_sizes[1] / 2;       // 400000
    const int ET = E + n;
    const int* srcA = ei;
    const int* dstA = ei + E;

    char* ws = (char*)d_ws;
    size_t off = 0;
    auto alloc = [&](size_t bytes) -> void* {
        void* p = ws + off;
        off += (bytes + 255) & ~(size_t)255;
        return p;
    };
    ushort_t* xb     = (ushort_t*)alloc((size_t)n * NFEAT * 2);
    ushort_t* feat1b = (ushort_t*)alloc((size_t)n * HID1 * 2);
    ushort_t* h1b    = (ushort_t*)alloc((size_t)n * HID1 * 2);
    ushort_t* feat2b = (ushort_t*)alloc((size_t)n * NOUT * 2);
    ushort_t* W1t    = (ushort_t*)alloc((size_t)NFEAT * HID1 * 2);
    ushort_t* W2t    = (ushort_t*)alloc((size_t)HID1 * NOUT * 2);
    float* el1 = (float*)alloc((size_t)n * NHEAD * 4);
    float* er1 = (float*)alloc((size_t)n * NHEAD * 4);
    float* el2 = (float*)alloc((size_t)n * 4);
    float* er2 = (float*)alloc((size_t)n * 4);
    float* wcsr1 = (float*)alloc((size_t)ET * NHEAD * 4);
    float* wcsr2 = (float*)alloc((size_t)ET * 4);
    int* indptr  = (int*)alloc((size_t)(n + 1) * 4);
    int* deg     = (int*)alloc((size_t)n * 4);
    int* cnt     = (int*)alloc((size_t)n * 4);
    int* csr     = (int*)alloc((size_t)ET * 4);
    int* csrd    = (int*)alloc((size_t)ET * 4);

    hipMemsetAsync(deg, 0, (size_t)n * 4, stream);
    hipMemsetAsync(cnt, 0, (size_t)n * 4, stream);

    // fused prep (cast + W transposes + hist)
    const int c0 = (n * NFEAT / 4) / 256;           // 12500
    const int c1 = c0 + (NFEAT * HID1) / 256;       // +512
    const int c2 = c1 + (HID1 * NOUT) / 256;        // +256
    const int c3 = c2 + (ET + 255) / 256;           // +1758
    k_prep<<<c3, 256, 0, stream>>>(x, xb, W1, W1t, W2, W2t, dstA, deg, n, E, c0, c1, c2);

    k_scan<<<1, 1024, 0, stream>>>(deg, indptr, n);
    k_fill<<<(ET + 255) / 256, 256, 0, stream>>>(srcA, dstA, E, n, indptr, cnt, csr, csrd);

    // layer 1
    k_gemm1<<<dim3(HID1 / 128, (n + 127) / 128), 256, 0, stream>>>(xb, W1t, feat1b, al1, ar1, el1, er1, n);
    k_wgt1<<<(ET * NHEAD + 255) / 256, 256, 0, stream>>>(csr, csrd, el1, er1, wcsr1, ET);
    k_agg1<<<n, 256, 0, stream>>>((const uint_t*)feat1b, wcsr1, b1, indptr, csr, (uint_t*)h1b, n);

    // layer 2
    k_gemm2<<<dim3(1, (n + 63) / 64), 256, 0, stream>>>(h1b, W2t, feat2b, al2, ar2, el2, er2, n);
    k_wgt2<<<(ET + 255) / 256, 256, 0, stream>>>(csr, csrd, el2, er2, wcsr2, ET);
    k_agg2<<<(n + 3) / 4, 256, 0, stream>>>((const uint_t*)feat2b, wcsr2, b2, indptr, csr, (float*)d_out, n);
}